// Round 3
// baseline (27.917 us; speedup 1.0000x reference)
//
#include <hip/hip_runtime.h>

// out[b,s,:] = vocab_weight[idx[b,s]] + pos_weight[s] + tokentype_weight[types[b,s]]
// B=8, S=2048, H=1024, fp32. Memory-bound gather+add.
//
// Layout trick: grid = S = 2048 blocks; block x handles tokens {x + k*2048}
// for k=0..7, i.e. the SAME position s=x in all 8 batches. So the pos row is
// loaded once per block (8x read reduction) and the two tokentype rows are
// loaded once and selected per token. Vocab rows are the only true gather.

#define HIDDEN 1024
#define SEQ 2048
#define NTOK (8 * SEQ)
#define BLOCKS SEQ
#define ITERS (NTOK / BLOCKS)   // 8

typedef float v4f __attribute__((ext_vector_type(4)));

__global__ __launch_bounds__(256) void embed_fused_kernel(
    const int* __restrict__ idx,
    const int* __restrict__ types,
    const float* __restrict__ vocab_w,
    const float* __restrict__ pos_w,
    const float* __restrict__ tt_w,
    float* __restrict__ out)
{
    const int s = blockIdx.x;          // position; same for all ITERS tokens
    const int t = threadIdx.x;         // 0..255, one float4 each

    // Hoist all index loads (wave-uniform scalar loads, overlap latency)
    int rows[ITERS], tts[ITERS];
#pragma unroll
    for (int k = 0; k < ITERS; ++k) {
        const int token = s + k * BLOCKS;
        rows[k] = idx[token];
        tts[k]  = types[token];
    }

    // Position row: loaded once, reused for all 8 tokens
    const v4f p = reinterpret_cast<const v4f*>(pos_w + (size_t)s * HIDDEN)[t];
    // Both tokentype rows (NUM_TOKENTYPES == 2): load once, select per token
    const v4f q0 = reinterpret_cast<const v4f*>(tt_w)[t];
    const v4f q1 = reinterpret_cast<const v4f*>(tt_w + HIDDEN)[t];

#pragma unroll
    for (int k = 0; k < ITERS; ++k) {
        const int token = s + k * BLOCKS;
        const v4f a = reinterpret_cast<const v4f*>(vocab_w + (size_t)rows[k] * HIDDEN)[t];
        const v4f q = tts[k] ? q1 : q0;
        v4f r = a + p + q;
        v4f* o = reinterpret_cast<v4f*>(out + (size_t)token * HIDDEN) + t;
        __builtin_nontemporal_store(r, o);
    }
}

extern "C" void kernel_launch(void* const* d_in, const int* in_sizes, int n_in,
                              void* d_out, int out_size, void* d_ws, size_t ws_size,
                              hipStream_t stream)
{
    const int*   idx     = (const int*)d_in[0];   // [B,S] int32
    const int*   types   = (const int*)d_in[1];   // [B,S] int32
    const float* vocab_w = (const float*)d_in[2]; // [VOCAB, H] fp32
    const float* pos_w   = (const float*)d_in[3]; // [S, H] fp32
    const float* tt_w    = (const float*)d_in[4]; // [NUM_TT, H] fp32
    float*       out     = (float*)d_out;         // [B,S,H] fp32

    embed_fused_kernel<<<BLOCKS, 256, 0, stream>>>(idx, types, vocab_w, pos_w, tt_w, out);
}

// Round 4
// 25.102 us; speedup vs baseline: 1.1122x; 1.1122x over previous
//
#include <hip/hip_runtime.h>

// out[b,s,:] = vocab_weight[idx[b,s]] + pos_weight[s] + tokentype_weight[types[b,s]]
// B=8, S=2048, H=1024, fp32. Memory-bound gather+add.
//
// Round-1 structure (fastest so far): one 256-thread block per token,
// each thread one float4 (perfectly coalesced 4KB row reads/writes).
// Single change vs round 1: nontemporal store on the output stream so the
// 67 MB write-once buffer doesn't evict the L3-resident vocab table.

#define HIDDEN 1024
#define SEQ 2048

typedef float v4f __attribute__((ext_vector_type(4)));

__global__ __launch_bounds__(256) void embed_fused_kernel(
    const int* __restrict__ idx,
    const int* __restrict__ types,
    const float* __restrict__ vocab_w,
    const float* __restrict__ pos_w,
    const float* __restrict__ tt_w,
    float* __restrict__ out)
{
    const int token = blockIdx.x;           // 0 .. B*S-1, one block per token row
    const int s     = token & (SEQ - 1);    // position within sequence
    const int row   = idx[token];           // vocab row (wave-uniform per block)
    const int tt    = types[token];         // tokentype row (wave-uniform)
    const int t     = threadIdx.x;          // 0..255, one float4 each

    const v4f a = reinterpret_cast<const v4f*>(vocab_w + (size_t)row * HIDDEN)[t];
    const v4f p = reinterpret_cast<const v4f*>(pos_w   + (size_t)s   * HIDDEN)[t];
    const v4f q = reinterpret_cast<const v4f*>(tt_w    + (size_t)tt  * HIDDEN)[t];

    v4f r = a + p + q;
    v4f* o = reinterpret_cast<v4f*>(out + (size_t)token * HIDDEN) + t;
    __builtin_nontemporal_store(r, o);
}

extern "C" void kernel_launch(void* const* d_in, const int* in_sizes, int n_in,
                              void* d_out, int out_size, void* d_ws, size_t ws_size,
                              hipStream_t stream)
{
    const int*   idx     = (const int*)d_in[0];   // [B,S] int32
    const int*   types   = (const int*)d_in[1];   // [B,S] int32
    const float* vocab_w = (const float*)d_in[2]; // [VOCAB, H] fp32
    const float* pos_w   = (const float*)d_in[3]; // [S, H] fp32
    const float* tt_w    = (const float*)d_in[4]; // [NUM_TT, H] fp32
    float*       out     = (float*)d_out;         // [B,S,H] fp32

    const int n_tokens = in_sizes[0];             // B*S = 16384
    embed_fused_kernel<<<n_tokens, 256, 0, stream>>>(idx, types, vocab_w, pos_w, tt_w, out);
}